// Round 6
// baseline (162.947 us; speedup 1.0000x reference)
//
#include <hip/hip_runtime.h>

#define NN 512
#define DIN 64
#define DH 32
#define HSTR 520   // h_t row stride (pad: 260 dw == 4 mod 32, keeps 16B alignment)

typedef __attribute__((ext_vector_type(8))) short short8;
typedef __attribute__((ext_vector_type(4))) short short4v;
typedef __attribute__((ext_vector_type(4))) float f32x4;

__device__ __forceinline__ float bf2f(unsigned short u) {
    return __uint_as_float(((unsigned)u) << 16);
}
__device__ __forceinline__ unsigned short f2bf(float x) {
    unsigned u = __float_as_uint(x);
    u += 0x7FFF + ((u >> 16) & 1);
    return (unsigned short)(u >> 16);
}

// Two blocks per (head, batch): blockIdx.x = (b*8 + h)*2 + hb, hb = i-row half.
// Each block: full projection (phase A), then phase B for its 256 i-rows.
// 512 threads = 8 waves; 2 blocks/CU.
__global__ __launch_bounds__(512, 4) void attn_kernel(
    const float* __restrict__ in_g,    // [B,512,64]
    const float* __restrict__ lin_g,   // [H,64,32]
    const float* __restrict__ asrc_g,  // [H,32]
    const float* __restrict__ atar_g,  // [H,32]
    float* __restrict__ msgs8)         // [B*8][512][32] fp32, slice = blockIdx.x>>1
{
    __shared__ unsigned short h_t[DH * HSTR];       // 33280 B: h_t[c*HSTR + m] = h[m][c]
    __shared__ float s_arr[NN], e1s[NN], e2s[NN];   // j-side: s, e^s, e^{0.2s}
    __shared__ float cng[NN], e1t[NN], e2t[NN];     // i-side: -t, e^t, e^{0.2t}
    __shared__ float dinv[NN / 2];                  // this block's 256 i-rows

    const int t = threadIdx.x;
    const int lane = t & 63, wv = t >> 6;
    const int l15 = lane & 15, quad = lane >> 4;
    const int hb   = blockIdx.x & 1;
    const int hIdx = (blockIdx.x >> 1) & 7;
    const int bIdx = blockIdx.x >> 4;

    const float as_lo = asrc_g[hIdx * 32 + l15];
    const float as_hi = asrc_g[hIdx * 32 + l15 + 16];
    const float at_lo = atar_g[hIdx * 32 + l15];
    const float at_hi = atar_g[hIdx * 32 + l15 + 16];

    // ---------- Phase A: full projection h = x @ W via MFMA (both halves do this) ----------
    short8 bfrag[2][2];
    {
        const float* lp = lin_g + hIdx * (DIN * DH);
        for (int nt = 0; nt < 2; ++nt)
            for (int ks = 0; ks < 2; ++ks)
                #pragma unroll
                for (int j = 0; j < 8; ++j)
                    bfrag[nt][ks][j] = (short)f2bf(lp[(ks * 32 + quad * 8 + j) * DH + l15 + nt * 16]);
    }
    const float* xb = in_g + (size_t)bIdx * (NN * DIN);
    for (int mi = 0; mi < 4; ++mi) {
        int mt = wv * 4 + mi;
        int row = mt * 16 + l15;
        const float* rp = xb + row * DIN + quad * 8;
        f32x4 x0 = *((const f32x4*)rp);
        f32x4 x1 = *((const f32x4*)(rp + 4));
        f32x4 x2 = *((const f32x4*)(rp + 32));
        f32x4 x3 = *((const f32x4*)(rp + 36));
        short8 a0, a1;
        #pragma unroll
        for (int j = 0; j < 4; ++j) {
            a0[j]     = (short)f2bf(x0[j]);
            a0[4 + j] = (short)f2bf(x1[j]);
            a1[j]     = (short)f2bf(x2[j]);
            a1[4 + j] = (short)f2bf(x3[j]);
        }
        f32x4 c0 = {0.f, 0.f, 0.f, 0.f}, c1 = {0.f, 0.f, 0.f, 0.f};
        c0 = __builtin_amdgcn_mfma_f32_16x16x32_bf16(a0, bfrag[0][0], c0, 0, 0, 0);
        c0 = __builtin_amdgcn_mfma_f32_16x16x32_bf16(a1, bfrag[0][1], c0, 0, 0, 0);
        c1 = __builtin_amdgcn_mfma_f32_16x16x32_bf16(a0, bfrag[1][0], c1, 0, 0, 0);
        c1 = __builtin_amdgcn_mfma_f32_16x16x32_bf16(a1, bfrag[1][1], c1, 0, 0, 0);
        float ps[4], pt[4];
        #pragma unroll
        for (int r = 0; r < 4; ++r) {
            int m = mt * 16 + quad * 4 + r;
            h_t[l15 * HSTR + m]        = f2bf(c0[r]);
            h_t[(l15 + 16) * HSTR + m] = f2bf(c1[r]);
            ps[r] = c0[r] * as_lo + c1[r] * as_hi;
            pt[r] = c0[r] * at_lo + c1[r] * at_hi;
        }
        #pragma unroll
        for (int off = 1; off <= 8; off <<= 1) {
            #pragma unroll
            for (int r = 0; r < 4; ++r) {
                ps[r] += __shfl_xor(ps[r], off, 64);
                pt[r] += __shfl_xor(pt[r], off, 64);
            }
        }
        if (l15 < 4) {
            int r = l15;
            int m = mt * 16 + quad * 4 + r;
            float s = ps[r], tt = pt[r];
            s_arr[m] = s;
            e1s[m] = expf(s);   e2s[m] = expf(0.2f * s);
            cng[m] = -tt;
            e1t[m] = expf(tt);  e2t[m] = expf(0.2f * tt);
        }
    }
    __syncthreads();

    // ---------- Phase B: this half's 256 i-rows. 16 row-tiles over 8 waves ----------
    float cn[2], t1[2], t2[2];
    int iR[2];
    #pragma unroll
    for (int rt = 0; rt < 2; ++rt) {
        int rw = hb * 256 + (wv * 2 + rt) * 16 + l15;   // global i-row
        iR[rt] = rw;
        cn[rt] = cng[rw]; t1[rt] = e1t[rw]; t2[rt] = e2t[rw];
    }
    f32x4 acc[2][2];
    float dacc[2];
    #pragma unroll
    for (int rt = 0; rt < 2; ++rt) {
        acc[rt][0] = (f32x4){0.f, 0.f, 0.f, 0.f};
        acc[rt][1] = (f32x4){0.f, 0.f, 0.f, 0.f};
        dacc[rt] = 0.f;
    }

    for (int kb = 0; kb < 16; ++kb) {
        const int j0 = kb * 32 + quad * 8;
        f32x4 sv0 = *(const f32x4*)&s_arr[j0], sv1 = *(const f32x4*)&s_arr[j0 + 4];
        f32x4 ev0 = *(const f32x4*)&e1s[j0],   ev1 = *(const f32x4*)&e1s[j0 + 4];
        f32x4 fv0 = *(const f32x4*)&e2s[j0],   fv1 = *(const f32x4*)&e2s[j0 + 4];
        short8 b0 = *(const short8*)&h_t[l15 * HSTR + j0];
        short8 b1 = *(const short8*)&h_t[(l15 + 16) * HSTR + j0];
        #pragma unroll
        for (int rt = 0; rt < 2; ++rt) {
            const bool selfkb = (kb == (iR[rt] >> 5));
            float w8[8];
            #pragma unroll
            for (int jj = 0; jj < 8; ++jj) {
                float sj = (jj < 4) ? sv0[jj & 3] : sv1[jj & 3];
                float e1 = (jj < 4) ? ev0[jj & 3] : ev1[jj & 3];
                float e2 = (jj < 4) ? fv0[jj & 3] : fv1[jj & 3];
                float w = (sj > cn[rt]) ? t1[rt] * e1 : t2[rt] * e2;
                if (selfkb && (j0 + jj == iR[rt])) w = 0.f;
                dacc[rt] += w;
                w8[jj] = w;
            }
            union { unsigned u[4]; short8 s8; } au;
            #pragma unroll
            for (int pp = 0; pp < 4; ++pp) {
                unsigned lo = __float_as_uint(w8[2 * pp])     + 0x8000u;
                unsigned hi = __float_as_uint(w8[2 * pp + 1]) + 0x8000u;
                au.u[pp] = (lo >> 16) | (hi & 0xffff0000u);
            }
            acc[rt][0] = __builtin_amdgcn_mfma_f32_16x16x32_bf16(au.s8, b0, acc[rt][0], 0, 0, 0);
            acc[rt][1] = __builtin_amdgcn_mfma_f32_16x16x32_bf16(au.s8, b1, acc[rt][1], 0, 0, 0);
        }
    }

    // denominator: reduce the 4 quads (same row lives in lanes sharing l15)
    #pragma unroll
    for (int rt = 0; rt < 2; ++rt) {
        float D = dacc[rt];
        D += __shfl_xor(D, 16, 64);
        D += __shfl_xor(D, 32, 64);
        if (quad == 0) dinv[iR[rt] - hb * 256] = 0.125f / D;   // local row; same-wave read below
    }

    float* mbase = msgs8 + (size_t)(blockIdx.x >> 1) * (NN * DH);
    #pragma unroll
    for (int rt = 0; rt < 2; ++rt) {
        #pragma unroll
        for (int half = 0; half < 2; ++half) {
            #pragma unroll
            for (int r = 0; r < 4; ++r) {
                int rloc = (wv * 2 + rt) * 16 + quad * 4 + r;
                int row = hb * 256 + rloc;
                mbase[row * DH + half * 16 + l15] = acc[rt][half][r] * dinv[rloc];
            }
        }
    }
}

// GRU-style gated update. 256 blocks x 256 threads, 64 rows/block.
// Sums the 8 head slices of msgs8 while staging msgv.
__global__ __launch_bounds__(256) void gru_kernel(
    const float* __restrict__ in_g,
    const float* __restrict__ hid_g,
    const float* __restrict__ bias_g,
    const float* __restrict__ Whr, const float* __restrict__ Whi,
    const float* __restrict__ Whm,
    const float* __restrict__ Wir, const float* __restrict__ bir,
    const float* __restrict__ Wii, const float* __restrict__ bii,
    const float* __restrict__ Win, const float* __restrict__ bin_,
    const float* __restrict__ msgs8,   // [B*8][512][32], slice = b*8+h
    float* __restrict__ out_g)
{
    __shared__ float xs[64 * 100];                // cols 0..63 = x, 64..95 = tanh(msum+bias)
    __shared__ unsigned short WtL[3 * 32 * 100];  // Wt[g][k][d] bf16 (96 d's used)

    const int t = threadIdx.x;
    const int rowbase = blockIdx.x * 64;
    const int bslice = blockIdx.x >> 3;           // batch of this block
    const int r0 = (blockIdx.x & 7) * 64;         // row offset within batch

    for (int idx = t; idx < 1024; idx += 256) {
        int fi = idx * 4;
        int row = fi >> 6, d = fi & 63;
        f32x4 v = *(const f32x4*)&in_g[(size_t)(rowbase + row) * 64 + d];
        *(f32x4*)&xs[row * 100 + d] = v;
    }
    for (int idx = t; idx < 2048; idx += 256) {
        int row = idx >> 5, k2 = idx & 31;
        size_t base = (size_t)bslice * (8 * NN * DH) + (size_t)(r0 + row) * DH + k2;
        float s = 0.f;
        #pragma unroll
        for (int h = 0; h < 8; ++h) s += msgs8[base + (size_t)h * (NN * DH)];
        xs[row * 100 + 64 + k2] = tanhf(s + bias_g[k2]);
    }
    for (int idx = t; idx < 9216; idx += 256) {
        int g = idx / 3072, rem = idx % 3072;
        int d = rem >> 5, k2 = rem & 31;
        float v;
        if (g == 0) v = (d < 64) ? Wir[d * 32 + k2] : Whr[(d - 64) * 32 + k2];
        else if (g == 1) v = (d < 64) ? Wii[d * 32 + k2] : Whi[(d - 64) * 32 + k2];
        else v = (d < 64) ? Win[d * 32 + k2] : Whm[(d - 64) * 32 + k2];
        WtL[(g * 32 + k2) * 100 + d] = f2bf(v);
    }
    __syncthreads();

    const int k = t & 31, rg = t >> 5;
    const unsigned short* wp0 = &WtL[(0 * 32 + k) * 100];
    const unsigned short* wp1 = &WtL[(1 * 32 + k) * 100];
    const unsigned short* wp2 = &WtL[(2 * 32 + k) * 100];

    float pr[8], pi[8], xn[8], hm[8];
    #pragma unroll
    for (int r = 0; r < 8; ++r) { pr[r] = 0.f; pi[r] = 0.f; xn[r] = 0.f; hm[r] = 0.f; }

    for (int d0 = 0; d0 < 64; d0 += 4) {
        short4v wr4 = *(const short4v*)&wp0[d0];
        short4v wi4 = *(const short4v*)&wp1[d0];
        short4v wn4 = *(const short4v*)&wp2[d0];
        float wr[4], wi[4], wn[4];
        #pragma unroll
        for (int jj = 0; jj < 4; ++jj) {
            wr[jj] = bf2f((unsigned short)wr4[jj]);
            wi[jj] = bf2f((unsigned short)wi4[jj]);
            wn[jj] = bf2f((unsigned short)wn4[jj]);
        }
        #pragma unroll
        for (int r = 0; r < 8; ++r) {
            f32x4 xv = *(const f32x4*)&xs[(rg * 8 + r) * 100 + d0];
            #pragma unroll
            for (int jj = 0; jj < 4; ++jj) {
                pr[r] += xv[jj] * wr[jj];
                pi[r] += xv[jj] * wi[jj];
                xn[r] += xv[jj] * wn[jj];
            }
        }
    }
    for (int d0 = 64; d0 < 96; d0 += 4) {
        short4v wr4 = *(const short4v*)&wp0[d0];
        short4v wi4 = *(const short4v*)&wp1[d0];
        short4v wn4 = *(const short4v*)&wp2[d0];
        float wr[4], wi[4], wn[4];
        #pragma unroll
        for (int jj = 0; jj < 4; ++jj) {
            wr[jj] = bf2f((unsigned short)wr4[jj]);
            wi[jj] = bf2f((unsigned short)wi4[jj]);
            wn[jj] = bf2f((unsigned short)wn4[jj]);
        }
        #pragma unroll
        for (int r = 0; r < 8; ++r) {
            f32x4 xv = *(const f32x4*)&xs[(rg * 8 + r) * 100 + d0];
            #pragma unroll
            for (int jj = 0; jj < 4; ++jj) {
                pr[r] += xv[jj] * wr[jj];
                pi[r] += xv[jj] * wi[jj];
                hm[r] += xv[jj] * wn[jj];
            }
        }
    }

    const float bir_k = bir[k], bii_k = bii[k], bin_k = bin_[k];
    #pragma unroll
    for (int r = 0; r < 8; ++r) {
        int row = rowbase + rg * 8 + r;
        float m  = 1.f / (1.f + expf(-(pr[r] + bir_k)));
        float ig = 1.f / (1.f + expf(-(pi[r] + bii_k)));
        float nn = tanhf(xn[r] + bin_k + m * hm[r]);
        float ho = hid_g[(size_t)row * 32 + k];
        out_g[(size_t)row * 32 + k] = ig * nn + (1.f - ig) * ho;
    }
}

extern "C" void kernel_launch(void* const* d_in, const int* in_sizes, int n_in,
                              void* d_out, int out_size, void* d_ws, size_t ws_size,
                              hipStream_t stream)
{
    const float* inputs = (const float*)d_in[0];
    const float* hidden = (const float*)d_in[1];
    const float* linear = (const float*)d_in[2];
    const float* bias   = (const float*)d_in[3];
    const float* asrc   = (const float*)d_in[4];
    const float* atar   = (const float*)d_in[5];
    const float* Whr    = (const float*)d_in[6];
    const float* Whi    = (const float*)d_in[7];
    const float* Whm    = (const float*)d_in[8];
    const float* Wir    = (const float*)d_in[9];
    const float* bir    = (const float*)d_in[10];
    const float* Wii    = (const float*)d_in[11];
    const float* bii    = (const float*)d_in[12];
    const float* Win    = (const float*)d_in[13];
    const float* bin_   = (const float*)d_in[14];

    float* msgs8 = (float*)d_ws;   // [B*8][512][32] fp32, 16 MB
    attn_kernel<<<dim3(512), dim3(512), 0, stream>>>(inputs, linear, asrc, atar, msgs8);
    gru_kernel<<<dim3(256), dim3(256), 0, stream>>>(inputs, hidden, bias,
                                                    Whr, Whi, Whm,
                                                    Wir, bir, Wii, bii, Win, bin_,
                                                    msgs8, (float*)d_out);
}

// Round 7
// 144.221 us; speedup vs baseline: 1.1298x; 1.1298x over previous
//
#include <hip/hip_runtime.h>

#define NN 512
#define DIN 64
#define DH 32
#define HSTR 520   // h_t row stride (pad: 260 dw == 4 mod 32, keeps 16B alignment)

typedef __attribute__((ext_vector_type(8))) short short8;
typedef __attribute__((ext_vector_type(4))) short short4v;
typedef __attribute__((ext_vector_type(4))) float f32x4;

__device__ __forceinline__ float bf2f(unsigned short u) {
    return __uint_as_float(((unsigned)u) << 16);
}
__device__ __forceinline__ unsigned short f2bf(float x) {
    unsigned u = __float_as_uint(x);
    u += 0x7FFF + ((u >> 16) & 1);
    return (unsigned short)(u >> 16);
}

// Two blocks per (head, batch): blockIdx.x = (b*8 + h)*2 + hb, hb = i-row half.
// Each block: full projection (phase A), then phase B for its 256 i-rows.
// 512 threads = 8 waves. NOTE: no min-waves arg — R6's (512,4) forced VGPR=64
// and spilled to scratch (FETCH 54 MB / WRITE 91 MB, attn 55 µs). Natural
// allocation ~88 VGPR still gives 2 blocks/CU without spills.
__global__ __launch_bounds__(512) void attn_kernel(
    const float* __restrict__ in_g,    // [B,512,64]
    const float* __restrict__ lin_g,   // [H,64,32]
    const float* __restrict__ asrc_g,  // [H,32]
    const float* __restrict__ atar_g,  // [H,32]
    float* __restrict__ msgs8)         // [B*8][512][32] fp32, slice = blockIdx.x>>1
{
    __shared__ unsigned short h_t[DH * HSTR];       // 33280 B: h_t[c*HSTR + m] = h[m][c]
    __shared__ float s_arr[NN], e1s[NN], e2s[NN];   // j-side: s, e^s, e^{0.2s}
    __shared__ float cng[NN], e1t[NN], e2t[NN];     // i-side: -t, e^t, e^{0.2t}
    __shared__ float dinv[NN / 2];                  // this block's 256 i-rows

    const int t = threadIdx.x;
    const int lane = t & 63, wv = t >> 6;
    const int l15 = lane & 15, quad = lane >> 4;
    const int hb   = blockIdx.x & 1;
    const int hIdx = (blockIdx.x >> 1) & 7;
    const int bIdx = blockIdx.x >> 4;

    const float as_lo = asrc_g[hIdx * 32 + l15];
    const float as_hi = asrc_g[hIdx * 32 + l15 + 16];
    const float at_lo = atar_g[hIdx * 32 + l15];
    const float at_hi = atar_g[hIdx * 32 + l15 + 16];

    // ---------- Phase A: full projection h = x @ W via MFMA (both halves do this) ----------
    short8 bfrag[2][2];
    {
        const float* lp = lin_g + hIdx * (DIN * DH);
        for (int nt = 0; nt < 2; ++nt)
            for (int ks = 0; ks < 2; ++ks)
                #pragma unroll
                for (int j = 0; j < 8; ++j)
                    bfrag[nt][ks][j] = (short)f2bf(lp[(ks * 32 + quad * 8 + j) * DH + l15 + nt * 16]);
    }
    const float* xb = in_g + (size_t)bIdx * (NN * DIN);
    for (int mi = 0; mi < 4; ++mi) {
        int mt = wv * 4 + mi;
        int row = mt * 16 + l15;
        const float* rp = xb + row * DIN + quad * 8;
        f32x4 x0 = *((const f32x4*)rp);
        f32x4 x1 = *((const f32x4*)(rp + 4));
        f32x4 x2 = *((const f32x4*)(rp + 32));
        f32x4 x3 = *((const f32x4*)(rp + 36));
        short8 a0, a1;
        #pragma unroll
        for (int j = 0; j < 4; ++j) {
            a0[j]     = (short)f2bf(x0[j]);
            a0[4 + j] = (short)f2bf(x1[j]);
            a1[j]     = (short)f2bf(x2[j]);
            a1[4 + j] = (short)f2bf(x3[j]);
        }
        f32x4 c0 = {0.f, 0.f, 0.f, 0.f}, c1 = {0.f, 0.f, 0.f, 0.f};
        c0 = __builtin_amdgcn_mfma_f32_16x16x32_bf16(a0, bfrag[0][0], c0, 0, 0, 0);
        c0 = __builtin_amdgcn_mfma_f32_16x16x32_bf16(a1, bfrag[0][1], c0, 0, 0, 0);
        c1 = __builtin_amdgcn_mfma_f32_16x16x32_bf16(a0, bfrag[1][0], c1, 0, 0, 0);
        c1 = __builtin_amdgcn_mfma_f32_16x16x32_bf16(a1, bfrag[1][1], c1, 0, 0, 0);
        float ps[4], pt[4];
        #pragma unroll
        for (int r = 0; r < 4; ++r) {
            int m = mt * 16 + quad * 4 + r;
            h_t[l15 * HSTR + m]        = f2bf(c0[r]);
            h_t[(l15 + 16) * HSTR + m] = f2bf(c1[r]);
            ps[r] = c0[r] * as_lo + c1[r] * as_hi;
            pt[r] = c0[r] * at_lo + c1[r] * at_hi;
        }
        #pragma unroll
        for (int off = 1; off <= 8; off <<= 1) {
            #pragma unroll
            for (int r = 0; r < 4; ++r) {
                ps[r] += __shfl_xor(ps[r], off, 64);
                pt[r] += __shfl_xor(pt[r], off, 64);
            }
        }
        if (l15 < 4) {
            int r = l15;
            int m = mt * 16 + quad * 4 + r;
            float s = ps[r], tt = pt[r];
            s_arr[m] = s;
            e1s[m] = expf(s);   e2s[m] = expf(0.2f * s);
            cng[m] = -tt;
            e1t[m] = expf(tt);  e2t[m] = expf(0.2f * tt);
        }
    }
    __syncthreads();

    // ---------- Phase B: this half's 256 i-rows. 16 row-tiles over 8 waves ----------
    float cn[2], t1[2], t2[2];
    int iR[2];
    #pragma unroll
    for (int rt = 0; rt < 2; ++rt) {
        int rw = hb * 256 + (wv * 2 + rt) * 16 + l15;   // global i-row
        iR[rt] = rw;
        cn[rt] = cng[rw]; t1[rt] = e1t[rw]; t2[rt] = e2t[rw];
    }
    f32x4 acc[2][2];
    float dacc[2];
    #pragma unroll
    for (int rt = 0; rt < 2; ++rt) {
        acc[rt][0] = (f32x4){0.f, 0.f, 0.f, 0.f};
        acc[rt][1] = (f32x4){0.f, 0.f, 0.f, 0.f};
        dacc[rt] = 0.f;
    }

    for (int kb = 0; kb < 16; ++kb) {
        const int j0 = kb * 32 + quad * 8;
        f32x4 sv0 = *(const f32x4*)&s_arr[j0], sv1 = *(const f32x4*)&s_arr[j0 + 4];
        f32x4 ev0 = *(const f32x4*)&e1s[j0],   ev1 = *(const f32x4*)&e1s[j0 + 4];
        f32x4 fv0 = *(const f32x4*)&e2s[j0],   fv1 = *(const f32x4*)&e2s[j0 + 4];
        short8 b0 = *(const short8*)&h_t[l15 * HSTR + j0];
        short8 b1 = *(const short8*)&h_t[(l15 + 16) * HSTR + j0];
        #pragma unroll
        for (int rt = 0; rt < 2; ++rt) {
            const bool selfkb = (kb == (iR[rt] >> 5));
            float w8[8];
            #pragma unroll
            for (int jj = 0; jj < 8; ++jj) {
                float sj = (jj < 4) ? sv0[jj & 3] : sv1[jj & 3];
                float e1 = (jj < 4) ? ev0[jj & 3] : ev1[jj & 3];
                float e2 = (jj < 4) ? fv0[jj & 3] : fv1[jj & 3];
                float w = (sj > cn[rt]) ? t1[rt] * e1 : t2[rt] * e2;
                if (selfkb && (j0 + jj == iR[rt])) w = 0.f;
                dacc[rt] += w;
                w8[jj] = w;
            }
            union { unsigned u[4]; short8 s8; } au;
            #pragma unroll
            for (int pp = 0; pp < 4; ++pp) {
                unsigned lo = __float_as_uint(w8[2 * pp])     + 0x8000u;
                unsigned hi = __float_as_uint(w8[2 * pp + 1]) + 0x8000u;
                au.u[pp] = (lo >> 16) | (hi & 0xffff0000u);
            }
            acc[rt][0] = __builtin_amdgcn_mfma_f32_16x16x32_bf16(au.s8, b0, acc[rt][0], 0, 0, 0);
            acc[rt][1] = __builtin_amdgcn_mfma_f32_16x16x32_bf16(au.s8, b1, acc[rt][1], 0, 0, 0);
        }
    }

    // denominator: reduce the 4 quads (same row lives in lanes sharing l15)
    #pragma unroll
    for (int rt = 0; rt < 2; ++rt) {
        float D = dacc[rt];
        D += __shfl_xor(D, 16, 64);
        D += __shfl_xor(D, 32, 64);
        if (quad == 0) dinv[iR[rt] - hb * 256] = 0.125f / D;   // local row; same-wave read below
    }

    float* mbase = msgs8 + (size_t)(blockIdx.x >> 1) * (NN * DH);
    #pragma unroll
    for (int rt = 0; rt < 2; ++rt) {
        #pragma unroll
        for (int half = 0; half < 2; ++half) {
            #pragma unroll
            for (int r = 0; r < 4; ++r) {
                int rloc = (wv * 2 + rt) * 16 + quad * 4 + r;
                int row = hb * 256 + rloc;
                mbase[row * DH + half * 16 + l15] = acc[rt][half][r] * dinv[rloc];
            }
        }
    }
}

// GRU-style gated update. 256 blocks x 256 threads, 64 rows/block.
// Sums the 8 head slices of msgs8 while staging msgv.
__global__ __launch_bounds__(256) void gru_kernel(
    const float* __restrict__ in_g,
    const float* __restrict__ hid_g,
    const float* __restrict__ bias_g,
    const float* __restrict__ Whr, const float* __restrict__ Whi,
    const float* __restrict__ Whm,
    const float* __restrict__ Wir, const float* __restrict__ bir,
    const float* __restrict__ Wii, const float* __restrict__ bii,
    const float* __restrict__ Win, const float* __restrict__ bin_,
    const float* __restrict__ msgs8,   // [B*8][512][32], slice = b*8+h
    float* __restrict__ out_g)
{
    __shared__ float xs[64 * 100];                // cols 0..63 = x, 64..95 = tanh(msum+bias)
    __shared__ unsigned short WtL[3 * 32 * 100];  // Wt[g][k][d] bf16 (96 d's used)

    const int t = threadIdx.x;
    const int rowbase = blockIdx.x * 64;
    const int bslice = blockIdx.x >> 3;           // batch of this block
    const int r0 = (blockIdx.x & 7) * 64;         // row offset within batch

    for (int idx = t; idx < 1024; idx += 256) {
        int fi = idx * 4;
        int row = fi >> 6, d = fi & 63;
        f32x4 v = *(const f32x4*)&in_g[(size_t)(rowbase + row) * 64 + d];
        *(f32x4*)&xs[row * 100 + d] = v;
    }
    for (int idx = t; idx < 2048; idx += 256) {
        int row = idx >> 5, k2 = idx & 31;
        size_t base = (size_t)bslice * (8 * NN * DH) + (size_t)(r0 + row) * DH + k2;
        float s = 0.f;
        #pragma unroll
        for (int h = 0; h < 8; ++h) s += msgs8[base + (size_t)h * (NN * DH)];
        xs[row * 100 + 64 + k2] = tanhf(s + bias_g[k2]);
    }
    for (int idx = t; idx < 9216; idx += 256) {
        int g = idx / 3072, rem = idx % 3072;
        int d = rem >> 5, k2 = rem & 31;
        float v;
        if (g == 0) v = (d < 64) ? Wir[d * 32 + k2] : Whr[(d - 64) * 32 + k2];
        else if (g == 1) v = (d < 64) ? Wii[d * 32 + k2] : Whi[(d - 64) * 32 + k2];
        else v = (d < 64) ? Win[d * 32 + k2] : Whm[(d - 64) * 32 + k2];
        WtL[(g * 32 + k2) * 100 + d] = f2bf(v);
    }
    __syncthreads();

    const int k = t & 31, rg = t >> 5;
    const unsigned short* wp0 = &WtL[(0 * 32 + k) * 100];
    const unsigned short* wp1 = &WtL[(1 * 32 + k) * 100];
    const unsigned short* wp2 = &WtL[(2 * 32 + k) * 100];

    float pr[8], pi[8], xn[8], hm[8];
    #pragma unroll
    for (int r = 0; r < 8; ++r) { pr[r] = 0.f; pi[r] = 0.f; xn[r] = 0.f; hm[r] = 0.f; }

    for (int d0 = 0; d0 < 64; d0 += 4) {
        short4v wr4 = *(const short4v*)&wp0[d0];
        short4v wi4 = *(const short4v*)&wp1[d0];
        short4v wn4 = *(const short4v*)&wp2[d0];
        float wr[4], wi[4], wn[4];
        #pragma unroll
        for (int jj = 0; jj < 4; ++jj) {
            wr[jj] = bf2f((unsigned short)wr4[jj]);
            wi[jj] = bf2f((unsigned short)wi4[jj]);
            wn[jj] = bf2f((unsigned short)wn4[jj]);
        }
        #pragma unroll
        for (int r = 0; r < 8; ++r) {
            f32x4 xv = *(const f32x4*)&xs[(rg * 8 + r) * 100 + d0];
            #pragma unroll
            for (int jj = 0; jj < 4; ++jj) {
                pr[r] += xv[jj] * wr[jj];
                pi[r] += xv[jj] * wi[jj];
                xn[r] += xv[jj] * wn[jj];
            }
        }
    }
    for (int d0 = 64; d0 < 96; d0 += 4) {
        short4v wr4 = *(const short4v*)&wp0[d0];
        short4v wi4 = *(const short4v*)&wp1[d0];
        short4v wn4 = *(const short4v*)&wp2[d0];
        float wr[4], wi[4], wn[4];
        #pragma unroll
        for (int jj = 0; jj < 4; ++jj) {
            wr[jj] = bf2f((unsigned short)wr4[jj]);
            wi[jj] = bf2f((unsigned short)wi4[jj]);
            wn[jj] = bf2f((unsigned short)wn4[jj]);
        }
        #pragma unroll
        for (int r = 0; r < 8; ++r) {
            f32x4 xv = *(const f32x4*)&xs[(rg * 8 + r) * 100 + d0];
            #pragma unroll
            for (int jj = 0; jj < 4; ++jj) {
                pr[r] += xv[jj] * wr[jj];
                pi[r] += xv[jj] * wi[jj];
                hm[r] += xv[jj] * wn[jj];
            }
        }
    }

    const float bir_k = bir[k], bii_k = bii[k], bin_k = bin_[k];
    #pragma unroll
    for (int r = 0; r < 8; ++r) {
        int row = rowbase + rg * 8 + r;
        float m  = 1.f / (1.f + expf(-(pr[r] + bir_k)));
        float ig = 1.f / (1.f + expf(-(pi[r] + bii_k)));
        float nn = tanhf(xn[r] + bin_k + m * hm[r]);
        float ho = hid_g[(size_t)row * 32 + k];
        out_g[(size_t)row * 32 + k] = ig * nn + (1.f - ig) * ho;
    }
}

extern "C" void kernel_launch(void* const* d_in, const int* in_sizes, int n_in,
                              void* d_out, int out_size, void* d_ws, size_t ws_size,
                              hipStream_t stream)
{
    const float* inputs = (const float*)d_in[0];
    const float* hidden = (const float*)d_in[1];
    const float* linear = (const float*)d_in[2];
    const float* bias   = (const float*)d_in[3];
    const float* asrc   = (const float*)d_in[4];
    const float* atar   = (const float*)d_in[5];
    const float* Whr    = (const float*)d_in[6];
    const float* Whi    = (const float*)d_in[7];
    const float* Whm    = (const float*)d_in[8];
    const float* Wir    = (const float*)d_in[9];
    const float* bir    = (const float*)d_in[10];
    const float* Wii    = (const float*)d_in[11];
    const float* bii    = (const float*)d_in[12];
    const float* Win    = (const float*)d_in[13];
    const float* bin_   = (const float*)d_in[14];

    float* msgs8 = (float*)d_ws;   // [B*8][512][32] fp32, 16 MB
    attn_kernel<<<dim3(512), dim3(512), 0, stream>>>(inputs, linear, asrc, atar, msgs8);
    gru_kernel<<<dim3(256), dim3(256), 0, stream>>>(inputs, hidden, bias,
                                                    Whr, Whi, Whm,
                                                    Wir, bir, Wii, bii, Win, bin_,
                                                    msgs8, (float*)d_out);
}